// Round 6
// baseline (419.817 us; speedup 1.0000x reference)
//
#include <hip/hip_runtime.h>

#define T_    1024
#define B_    2
#define D_    1024
#define E_    12
#define TOPK  4
#define ED_   256
#define HD_   64
#define H_    4
#define N_    (T_*B_)      // 2048 tokens
#define NROW  (N_*TOPK)    // 8192 (n,k) rows
#define PB_MAX 268         // max 32-row expert chunks: 8192/32 + 12
#define KR_   768          // split-precision K for reduce: [a_hi|a_lo|a_hi]

typedef __bf16 bf16x8 __attribute__((ext_vector_type(8)));
typedef float  f32x4  __attribute__((ext_vector_type(4)));

__device__ __forceinline__ float sc_() { return 0.35355339059327373f; } // 64^-0.25

__device__ __forceinline__ void async16(const void* g, void* l) {
    __builtin_amdgcn_global_load_lds((const __attribute__((address_space(1))) void*)g,
                                     (__attribute__((address_space(3))) void*)l, 16, 0, 0);
}

// ---------------- one-time: wgT[e][d] = wg[d][e] (f32, 48 KB) ----------------
__global__ void castwg_kernel(const float* __restrict__ wg, float* __restrict__ wgT) {
    int d = blockIdx.x * 256 + threadIdx.x;   // grid 4 x 256
#pragma unroll
    for (int e = 0; e < E_; ++e) wgT[e * D_ + d] = wg[d * E_ + e];
}

// ---------------- gating: wave per token, coalesced float4 dots --------------
__global__ void __launch_bounds__(256)
gate_kernel(const float* __restrict__ x, const float* __restrict__ wgT,
            float* __restrict__ gates, int* __restrict__ idx,
            int* __restrict__ counts) {
    int w = threadIdx.x >> 6, L = threadIdx.x & 63;
    int n = blockIdx.x * 4 + w;
    const float* xr = x + (size_t)n * D_;
    float acc[E_];
#pragma unroll
    for (int e = 0; e < E_; ++e) acc[e] = 0.f;
#pragma unroll
    for (int it = 0; it < 4; ++it) {
        float4 xv = *(const float4*)(xr + it * 256 + L * 4);
#pragma unroll
        for (int e = 0; e < E_; ++e) {
            float4 wv = *(const float4*)(wgT + e * D_ + it * 256 + L * 4);
            acc[e] += xv.x * wv.x + xv.y * wv.y + xv.z * wv.z + xv.w * wv.w;
        }
    }
#pragma unroll
    for (int e = 0; e < E_; ++e) {
        float v = acc[e];
        for (int o = 32; o > 0; o >>= 1) v += __shfl_down(v, o);
        acc[e] = v;
    }
    if (L == 0) {
        float mx = acc[0];
        for (int e = 1; e < E_; ++e) mx = fmaxf(mx, acc[e]);
        float s = 0.f, pr[E_];
        for (int e = 0; e < E_; ++e) { pr[e] = expf(acc[e] - mx); s += pr[e]; }
        float inv = 1.f / s;
        for (int e = 0; e < E_; ++e) pr[e] *= inv;
        for (int k = 0; k < TOPK; ++k) {
            int be = 0; float bv = -1.f;
            for (int e = 0; e < E_; ++e) if (pr[e] > bv) { bv = pr[e]; be = e; }
            gates[n * TOPK + k] = bv;
            idx[n * TOPK + k] = be;
            pr[be] = -1.f;
            atomicAdd(&counts[be], 1);
        }
    }
}

// ---------------- scan: offsets + 32-row expert chunk map --------------------
__global__ void scan_kernel(const int* __restrict__ counts, int* __restrict__ offs,
                            int* __restrict__ rbe2, int* __restrict__ rbs2, int* __restrict__ rbc2) {
    if (threadIdx.x == 0 && blockIdx.x == 0) {
        int o = 0;
        for (int e = 0; e < E_; ++e) { offs[e] = o; o += counts[e]; }
        offs[E_] = o;
        int nb2 = 0;
        for (int e = 0; e < E_; ++e) {
            int c = counts[e];
            for (int s = 0; s < c; s += 32) {
                rbe2[nb2] = e; rbs2[nb2] = offs[e] + s;
                rbc2[nb2] = (c - s < 32) ? (c - s) : 32; ++nb2;
            }
        }
        for (; nb2 < PB_MAX; ++nb2) { rbe2[nb2] = 0; rbs2[nb2] = 0; rbc2[nb2] = 0; }
    }
}

// ---------------- scatter rows into expert-grouped perm ----------------------
__global__ void scatter_kernel(const int* __restrict__ idx, const int* __restrict__ offs,
                               int* __restrict__ cur, int* __restrict__ perm) {
    int r = blockIdx.x * 256 + threadIdx.x;   // 8192 rows
    int e = idx[r];
    int p = atomicAdd(&cur[e], 1);
    perm[offs[e] + p] = r;
}

// ---------------- one-time casts ---------------------------------------------
__global__ void castx_kernel(const float* __restrict__ x, ushort* __restrict__ xb) {
    int t = blockIdx.x * 256 + threadIdx.x;
    float4 v = *(const float4*)(x + (size_t)t * 4);
    union { __bf16 h[4]; uint2 u; } pk;
    pk.h[0] = (__bf16)v.x; pk.h[1] = (__bf16)v.y;
    pk.h[2] = (__bf16)v.z; pk.h[3] = (__bf16)v.w;
    *(uint2*)(xb + (size_t)t * 4) = pk.u;
}

// grid (12,16,4): e, 64-d tile, 64-ed tile.  wmapT[e][ed][d] = bf16(w_map[e][d][ed])
__global__ void castw_kernel(const float* __restrict__ wmap, ushort* __restrict__ wmapT) {
    int e = blockIdx.x, dt = blockIdx.y, et = blockIdx.z;
    __shared__ float ls[64][65];
    int c = threadIdx.x & 63, rg = threadIdx.x >> 6;
    const float* src = wmap + (size_t)e * (D_ * ED_) + (size_t)(dt * 64) * ED_ + et * 64;
#pragma unroll
    for (int q = 0; q < 16; ++q) {
        int r = q * 4 + rg;
        ls[r][c] = src[(size_t)r * ED_ + c];
    }
    __syncthreads();
    ushort* dst = wmapT + ((size_t)e << 18) + (size_t)(et * 64) * 1024 + dt * 64;
#pragma unroll
    for (int q = 0; q < 16; ++q) {
        int r = q * 4 + rg;
        union { __bf16 h; ushort u; } cv; cv.h = (__bf16)ls[c][r];
        dst[(size_t)r * 1024 + c] = cv.u;
    }
}

// grid (2,16,4): which, 64-d tile, 64-ed tile. wT[ed][d] = bf16(w[d][ed])
__global__ void castwkv_kernel(const float* __restrict__ wk, const float* __restrict__ wv,
                               ushort* __restrict__ wkT, ushort* __restrict__ wvT) {
    int which = blockIdx.x, dt = blockIdx.y, et = blockIdx.z;
    const float* w = which ? wv : wk;
    ushort* wT = which ? wvT : wkT;
    __shared__ float ls[64][65];
    int c = threadIdx.x & 63, rg = threadIdx.x >> 6;
    const float* src = w + (size_t)(dt * 64) * ED_ + et * 64;
#pragma unroll
    for (int q = 0; q < 16; ++q) {
        int r = q * 4 + rg;
        ls[r][c] = src[(size_t)r * ED_ + c];
    }
    __syncthreads();
    ushort* dst = wT + (size_t)(et * 64) * 1024 + dt * 64;
#pragma unroll
    for (int q = 0; q < 16; ++q) {
        int r = q * 4 + rg;
        union { __bf16 h; ushort u; } cv; cv.h = (__bf16)ls[c][r];
        dst[(size_t)r * 1024 + c] = cv.u;
    }
}

// grid (12,4,16): e, 64-ed tile, 64-d tile.
// wredT3[e][d][k]: k in [0,256)=w_hi[ed], [256,512)=w_hi[ed], [512,768)=w_lo[ed]
__global__ void castwred_kernel(const float* __restrict__ wred, ushort* __restrict__ wredT3) {
    int e = blockIdx.x, et = blockIdx.y, dt = blockIdx.z;
    __shared__ float ls[64][65];
    int c = threadIdx.x & 63, rg = threadIdx.x >> 6;
    const float* src = wred + (size_t)e * (ED_ * D_) + (size_t)(et * 64) * D_ + dt * 64;
#pragma unroll
    for (int q = 0; q < 16; ++q) {
        int r = q * 4 + rg;           // ed-local
        ls[r][c] = src[(size_t)r * D_ + c];
    }
    __syncthreads();
    ushort* dst = wredT3 + (size_t)e * (D_ * KR_) + (size_t)(dt * 64) * KR_ + et * 64;
#pragma unroll
    for (int q = 0; q < 16; ++q) {
        int r = q * 4 + rg;           // d-local
        float v = ls[c][r];
        union { __bf16 h; ushort u; } hi; hi.h = (__bf16)v;
        float lo = v - (float)hi.h;
        union { __bf16 h; ushort u; } lov; lov.h = (__bf16)lo;
        dst[(size_t)r * KR_ + c] = hi.u;
        dst[(size_t)r * KR_ + 256 + c] = hi.u;
        dst[(size_t)r * KR_ + 512 + c] = lov.u;
    }
}

// ---------------- k/v projection as bf16 MFMA GEMM ---------------------------
__global__ void __launch_bounds__(256)
kv_mfma(const ushort* __restrict__ keyb, const ushort* __restrict__ valb,
        const ushort* __restrict__ wkT, const ushort* __restrict__ wvT,
        ushort* __restrict__ kpb, ushort* __restrict__ vpT) {
    int which = blockIdx.y;
    const ushort* xb = which ? valb : keyb;
    const ushort* wT = which ? wvT : wkT;
    int m0 = blockIdx.x * 32;
    int b = m0 >> 10, t0 = m0 & 1023;
    int tid = threadIdx.x, w = tid >> 6, L = tid & 63;
    __shared__ __align__(16) ushort As[2][32 * 64];
    __shared__ __align__(16) ushort Bs[2][4 * 64 * 64];

    int swz = ((L & 7) ^ ((L >> 3) & 7)) * 8;
    int an = (((t0 + w * 8 + (L >> 3)) << 1) | b);
    const ushort* asrc = xb + (size_t)an * 1024 + swz;
    const ushort* bsrc = wT + (size_t)(w * 64 + (L >> 3)) * 1024 + swz;

    f32x4 acc[2][4];
#pragma unroll
    for (int mt = 0; mt < 2; ++mt)
#pragma unroll
        for (int nt = 0; nt < 4; ++nt) acc[mt][nt] = (f32x4){0.f, 0.f, 0.f, 0.f};

    auto stage = [&](int kt, int bf) {
        async16(asrc + kt * 64, &As[bf][w * 512]);
#pragma unroll
        for (int q = 0; q < 8; ++q)
            async16(bsrc + (size_t)q * 8192 + kt * 64, &Bs[bf][(w * 64 + q * 8) * 64]);
    };
    auto compute = [&](int bf) {
        const ushort* AB = As[bf];
        const ushort* BB = Bs[bf] + w * 4096;
#pragma unroll
        for (int ks = 0; ks < 2; ++ks) {
            int phys = (((ks * 4 + (L >> 4)) ^ (L & 7))) * 8;
            bf16x8 a0 = *(const bf16x8*)(AB + (L & 15) * 64 + phys);
            bf16x8 a1 = *(const bf16x8*)(AB + (16 + (L & 15)) * 64 + phys);
#pragma unroll
            for (int nt = 0; nt < 4; ++nt) {
                bf16x8 bfr = *(const bf16x8*)(BB + (nt * 16 + (L & 15)) * 64 + phys);
                acc[0][nt] = __builtin_amdgcn_mfma_f32_16x16x32_bf16(a0, bfr, acc[0][nt], 0, 0, 0);
                acc[1][nt] = __builtin_amdgcn_mfma_f32_16x16x32_bf16(a1, bfr, acc[1][nt], 0, 0, 0);
            }
        }
    };

    stage(0, 0);
    for (int t = 0; t < 16; ++t) {
        __syncthreads();
        if (t < 15) stage(t + 1, (t + 1) & 1);
        compute(t & 1);
    }

#pragma unroll
    for (int mt = 0; mt < 2; ++mt)
#pragma unroll
        for (int nt = 0; nt < 4; ++nt) {
            int ed = w * 64 + nt * 16 + (L & 15);
            int tb = t0 + mt * 16 + (L >> 4) * 4;
            if (which == 0) {
#pragma unroll
                for (int r = 0; r < 4; ++r) {
                    union { __bf16 h; ushort u; } cv;
                    cv.h = (__bf16)(acc[mt][nt][r] * sc_());
                    kpb[((size_t)((b << 10) + tb + r)) * ED_ + ed] = cv.u;
                }
            } else {
                int h = ed >> 6, d = ed & 63;
                union { __bf16 h4[4]; uint2 u; } pk;
#pragma unroll
                for (int r = 0; r < 4; ++r) pk.h4[r] = (__bf16)acc[mt][nt][r];
                *(uint2*)&vpT[((size_t)((b * 4 + h) * 64 + d)) * 1024 + tb] = pk.u;
            }
        }
}

// ---------------- q projection as bf16 MFMA GEMM per 32-row expert chunk -----
__global__ void __launch_bounds__(256)
qproj_mfma(const ushort* __restrict__ xb, const ushort* __restrict__ wmapT,
           const int* __restrict__ perm,
           const int* __restrict__ rbe2, const int* __restrict__ rbs2,
           const int* __restrict__ rbc2,
           float* __restrict__ qp, ushort* __restrict__ qpb) {
    int blk = blockIdx.x;
    int nr = rbc2[blk];
    if (nr == 0) return;
    int e = rbe2[blk], rs = rbs2[blk];
    int tid = threadIdx.x, w = tid >> 6, L = tid & 63;
    __shared__ __align__(16) ushort As[2][32 * 64];
    __shared__ __align__(16) ushort Bs[2][4 * 64 * 64];
    __shared__ int rows2[32];
    if (tid < 32) rows2[tid] = (tid < nr) ? perm[rs + tid] : -1;
    __syncthreads();

    int swz = ((L & 7) ^ ((L >> 3) & 7)) * 8;
    int ar = rows2[w * 8 + (L >> 3)];
    const ushort* asrc = xb + (size_t)((ar < 0 ? 0 : ar) >> 2) * 1024 + swz;
    const ushort* bsrc = wmapT + ((size_t)e << 18) + (size_t)(w * 64 + (L >> 3)) * 1024 + swz;

    f32x4 acc[2][4];
#pragma unroll
    for (int mt = 0; mt < 2; ++mt)
#pragma unroll
        for (int nt = 0; nt < 4; ++nt) acc[mt][nt] = (f32x4){0.f, 0.f, 0.f, 0.f};

    auto stage = [&](int kt, int bf) {
        async16(asrc + kt * 64, &As[bf][w * 512]);
#pragma unroll
        for (int q = 0; q < 8; ++q)
            async16(bsrc + (size_t)q * 8192 + kt * 64, &Bs[bf][(w * 64 + q * 8) * 64]);
    };
    auto compute = [&](int bf) {
        const ushort* AB = As[bf];
        const ushort* BB = Bs[bf] + w * 4096;
#pragma unroll
        for (int ks = 0; ks < 2; ++ks) {
            int phys = (((ks * 4 + (L >> 4)) ^ (L & 7))) * 8;
            bf16x8 a0 = *(const bf16x8*)(AB + (L & 15) * 64 + phys);
            bf16x8 a1 = *(const bf16x8*)(AB + (16 + (L & 15)) * 64 + phys);
#pragma unroll
            for (int nt = 0; nt < 4; ++nt) {
                bf16x8 b = *(const bf16x8*)(BB + (nt * 16 + (L & 15)) * 64 + phys);
                acc[0][nt] = __builtin_amdgcn_mfma_f32_16x16x32_bf16(a0, b, acc[0][nt], 0, 0, 0);
                acc[1][nt] = __builtin_amdgcn_mfma_f32_16x16x32_bf16(a1, b, acc[1][nt], 0, 0, 0);
            }
        }
    };

    stage(0, 0);
    for (int t = 0; t < 16; ++t) {
        __syncthreads();
        if (t < 15) stage(t + 1, (t + 1) & 1);
        compute(t & 1);
    }

#pragma unroll
    for (int mt = 0; mt < 2; ++mt)
#pragma unroll
        for (int nt = 0; nt < 4; ++nt) {
            int n = w * 64 + nt * 16 + (L & 15);
#pragma unroll
            for (int r = 0; r < 4; ++r) {
                int m = mt * 16 + (L >> 4) * 4 + r;
                int rowg = rows2[m];
                if (rowg >= 0) {
                    float v = acc[mt][nt][r] * sc_();
                    qp[(size_t)rowg * ED_ + n] = v;
                    union { __bf16 h; ushort u; } cv; cv.h = (__bf16)v;
                    qpb[(size_t)rowg * ED_ + n] = cv.u;
                }
            }
        }
}

// ---------------- rel bias table: rel[bkh,i,p] = q_row . rpe[h,:,p] ----------
__global__ void rel_kernel(const float* __restrict__ qp, const float* __restrict__ rpe,
                           float* __restrict__ rel) {
    int Rr = blockIdx.x * 2 + (threadIdx.x >> 7);
    int p = threadIdx.x & 127;
    int i = Rr & 1023, h = (Rr >> 10) & 3, kk = (Rr >> 12) & 3, bb = Rr >> 14;
    int row = ((i * 2 + bb) << 2) | kk;
    int qbase = __builtin_amdgcn_readfirstlane(row * ED_ + h * HD_);
    int hbase = __builtin_amdgcn_readfirstlane(h * HD_);
    float acc = 0.f;
    for (int d = 0; d < HD_; ++d)
        acc += qp[qbase + d] * rpe[(hbase + d) * 129 + p];
    rel[Rr * 128 + p] = acc;
}

// ---------------- MFMA flash attention (bf16, no-max softmax) ----------------
// epilogue writes split-precision azd[row][768] = [a_hi | a_lo | a_hi] (bf16)
__global__ void __launch_bounds__(256)
attn_kernel(const ushort* __restrict__ qpb, const ushort* __restrict__ kpb,
            const ushort* __restrict__ vpT, const float* __restrict__ rel,
            const float* __restrict__ gates, ushort* __restrict__ azd) {
    __shared__ __align__(16) ushort Ks[2][64 * 64];
    __shared__ __align__(16) ushort Vs[2][64 * 64];
    __shared__ __align__(16) ushort Ps[4][16 * 64];

    const int tid = threadIdx.x;
    const int w = tid >> 6, L = tid & 63;
    const int bkh = blockIdx.x & 31, it = blockIdx.x >> 5;
    const int h = bkh & 3, kk = (bkh >> 2) & 3, bb = bkh >> 4;
    const int i0w = it * 64 + w * 16;
    const int iL = i0w + (L & 15);
    const int row = ((iL * 2 + bb) << 2) | kk;

    const ushort* qrow = qpb + row * ED_ + h * HD_;
    bf16x8 qf0 = *(const bf16x8*)(qrow + (L >> 4) * 8);
    bf16x8 qf1 = *(const bf16x8*)(qrow + 32 + (L >> 4) * 8);

    const float* relrow = rel + ((size_t)((bkh << 10) + iL)) * 128;
    float rel_lo = relrow[1], rel_hi = relrow[127];
    float gate = gates[row];

    f32x4 O[4];
#pragma unroll
    for (int mf = 0; mf < 4; ++mf) O[mf] = (f32x4){0.f, 0.f, 0.f, 0.f};
    float l_acc = 0.f;

    const ushort* ksrc = kpb + (size_t)(bb << 10) * ED_ + h * HD_;
    const ushort* vsrc = vpT + (size_t)((bb * 4 + h) * 64) * 1024;

    auto stage = [&](int t, int bf) {
        int j0 = t * 64;
#pragma unroll
        for (int q = 0; q < 2; ++q) {
            int r = L >> 3;
            int c = (L & 7) ^ r;
            const ushort* src = ksrc + (size_t)(j0 + w * 16 + q * 8 + r) * ED_ + c * 8;
            async16(src, &Ks[bf][(w * 16 + q * 8) * 64]);
        }
#pragma unroll
        for (int q = 0; q < 2; ++q) {
            int r = L >> 3;
            int d = w * 16 + q * 8 + r;
            int c = (L & 7) ^ (d & 7);
            const ushort* src = vsrc + (size_t)d * 1024 + j0 + c * 8;
            async16(src, &Vs[bf][(w * 16 + q * 8) * 64]);
        }
    };

    auto compute = [&](int bf, int j0) {
        const ushort* KB = Ks[bf];
        const ushort* VB = Vs[bf];
        ushort* PW = Ps[w];
#pragma unroll
        for (int jf = 0; jf < 4; ++jf) {
            int jrow = jf * 16 + (L & 15);
            bf16x8 a0 = *(const bf16x8*)(KB + jrow * 64 + (((L >> 4)) ^ (L & 7)) * 8);
            bf16x8 a1 = *(const bf16x8*)(KB + jrow * 64 + ((4 + (L >> 4)) ^ (L & 7)) * 8);
            f32x4 s = (f32x4){0.f, 0.f, 0.f, 0.f};
            s = __builtin_amdgcn_mfma_f32_16x16x32_bf16(a0, qf0, s, 0, 0, 0);
            s = __builtin_amdgcn_mfma_f32_16x16x32_bf16(a1, qf1, s, 0, 0, 0);
            int jlo = j0 + jf * 16;
            int jbase = jlo + (L >> 4) * 4;
            float pv[4];
            if (jlo >= i0w + 78) {
#pragma unroll
                for (int r = 0; r < 4; ++r) pv[r] = __expf(s[r] + rel_hi);
            } else if (jlo <= i0w - 78) {
#pragma unroll
                for (int r = 0; r < 4; ++r) pv[r] = __expf(s[r] + rel_lo);
            } else {
#pragma unroll
                for (int r = 0; r < 4; ++r) {
                    int dj = jbase + r - iL;
                    dj = dj < -63 ? -63 : (dj > 63 ? 63 : dj);
                    pv[r] = __expf(s[r] + relrow[dj + 64]);
                }
            }
            l_acc += (pv[0] + pv[1]) + (pv[2] + pv[3]);
            union { __bf16 h4[4]; uint2 u; } pk;
#pragma unroll
            for (int r = 0; r < 4; ++r) pk.h4[r] = (__bf16)pv[r];
            int iloc = L & 15;
            int chunk = jf * 2 + ((L >> 4) >> 1);
            int phys = chunk ^ (iloc & 7);
            *(uint2*)(PW + iloc * 64 + phys * 8 + ((L >> 4) & 1) * 4) = pk.u;
        }
#pragma unroll
        for (int ks = 0; ks < 2; ++ks) {
            int c = ks * 4 + (L >> 4);
            int phys = c ^ (L & 7);
            bf16x8 pf = *(const bf16x8*)(PW + (L & 15) * 64 + phys * 8);
#pragma unroll
            for (int mf = 0; mf < 4; ++mf) {
                bf16x8 vf = *(const bf16x8*)(VB + (mf * 16 + (L & 15)) * 64 + phys * 8);
                O[mf] = __builtin_amdgcn_mfma_f32_16x16x32_bf16(vf, pf, O[mf], 0, 0, 0);
            }
        }
    };

    stage(0, 0);
    for (int t = 0; t < 16; ++t) {
        __syncthreads();
        if (t < 15) stage(t + 1, (t + 1) & 1);
        compute(t & 1, t * 64);
    }

    l_acc += __shfl_xor(l_acc, 16);
    l_acc += __shfl_xor(l_acc, 32);
    float inv = gate / l_acc;
    ushort* azrow = azd + (size_t)row * KR_ + h * HD_;
#pragma unroll
    for (int mf = 0; mf < 4; ++mf) {
        union { __bf16 h4[4]; uint2 u; } hi, lo;
#pragma unroll
        for (int r = 0; r < 4; ++r) {
            float v = O[mf][r] * inv;
            hi.h4[r] = (__bf16)v;
            lo.h4[r] = (__bf16)(v - (float)hi.h4[r]);
        }
        int off = mf * 16 + (L >> 4) * 4;
        *(uint2*)(azrow + off) = hi.u;
        *(uint2*)(azrow + 256 + off) = lo.u;
        *(uint2*)(azrow + 512 + off) = hi.u;
    }
}

// ---------------- expert reduce as bf16 MFMA (split precision, K=768) --------
__global__ void __launch_bounds__(256)
reduce_mfma(const ushort* __restrict__ azd, const ushort* __restrict__ wredT3,
            const int* __restrict__ perm,
            const int* __restrict__ rbe2, const int* __restrict__ rbs2,
            const int* __restrict__ rbc2, float* __restrict__ z4) {
    int blk = blockIdx.x;
    int nr = rbc2[blk];
    if (nr == 0) return;
    int e = rbe2[blk], rs = rbs2[blk];
    int n0 = blockIdx.y * 256;
    int tid = threadIdx.x, w = tid >> 6, L = tid & 63;
    __shared__ __align__(16) ushort As[2][32 * 64];
    __shared__ __align__(16) ushort Bs[2][4 * 64 * 64];
    __shared__ int rows2[32];
    if (tid < 32) rows2[tid] = (tid < nr) ? perm[rs + tid] : -1;
    __syncthreads();

    int swz = ((L & 7) ^ ((L >> 3) & 7)) * 8;
    int ar = rows2[w * 8 + (L >> 3)];
    const ushort* asrc = azd + (size_t)(ar < 0 ? 0 : ar) * KR_ + swz;
    const ushort* bsrc = wredT3 + (size_t)e * (D_ * KR_)
                       + (size_t)(n0 + w * 64 + (L >> 3)) * KR_ + swz;

    f32x4 acc[2][4];
#pragma unroll
    for (int mt = 0; mt < 2; ++mt)
#pragma unroll
        for (int nt = 0; nt < 4; ++nt) acc[mt][nt] = (f32x4){0.f, 0.f, 0.f, 0.f};

    auto stage = [&](int kt, int bf) {
        async16(asrc + kt * 64, &As[bf][w * 512]);
#pragma unroll
        for (int q = 0; q < 8; ++q)
            async16(bsrc + (size_t)q * (8 * KR_) + kt * 64, &Bs[bf][(w * 64 + q * 8) * 64]);
    };
    auto compute = [&](int bf) {
        const ushort* AB = As[bf];
        const ushort* BB = Bs[bf] + w * 4096;
#pragma unroll
        for (int ks = 0; ks < 2; ++ks) {
            int phys = (((ks * 4 + (L >> 4)) ^ (L & 7))) * 8;
            bf16x8 a0 = *(const bf16x8*)(AB + (L & 15) * 64 + phys);
            bf16x8 a1 = *(const bf16x8*)(AB + (16 + (L & 15)) * 64 + phys);
#pragma unroll
            for (int nt = 0; nt < 4; ++nt) {
                bf16x8 b = *(const bf16x8*)(BB + (nt * 16 + (L & 15)) * 64 + phys);
                acc[0][nt] = __builtin_amdgcn_mfma_f32_16x16x32_bf16(a0, b, acc[0][nt], 0, 0, 0);
                acc[1][nt] = __builtin_amdgcn_mfma_f32_16x16x32_bf16(a1, b, acc[1][nt], 0, 0, 0);
            }
        }
    };

    stage(0, 0);
    for (int t = 0; t < 12; ++t) {       // K = 768 -> 12 tiles of 64
        __syncthreads();
        if (t < 11) stage(t + 1, (t + 1) & 1);
        compute(t & 1);
    }

#pragma unroll
    for (int mt = 0; mt < 2; ++mt)
#pragma unroll
        for (int nt = 0; nt < 4; ++nt) {
            int n = n0 + w * 64 + nt * 16 + (L & 15);
#pragma unroll
            for (int r = 0; r < 4; ++r) {
                int m = mt * 16 + (L >> 4) * 4 + r;
                int rowg = rows2[m];
                if (rowg >= 0) z4[(size_t)rowg * D_ + n] = acc[mt][nt][r];
            }
        }
}

// ---------------- combine: out[n] = sum_k z4[n*4+k] --------------------------
__global__ void combine_out(const float* __restrict__ z4, float* __restrict__ out) {
    int t = blockIdx.x * 256 + threadIdx.x;     // N_*D_/4 threads
    int n = t >> 8, d0 = (t & 255) * 4;
    const float* zr = z4 + (size_t)(n * 4) * D_ + d0;
    float4 a = *(const float4*)(zr);
    float4 b = *(const float4*)(zr + D_);
    float4 c = *(const float4*)(zr + 2 * D_);
    float4 d = *(const float4*)(zr + 3 * D_);
    float4 s = make_float4(a.x + b.x + c.x + d.x, a.y + b.y + c.y + d.y,
                           a.z + b.z + c.z + d.z, a.w + b.w + c.w + d.w);
    *(float4*)(out + (size_t)n * D_ + d0) = s;
}

// ---------------- launcher ---------------------------------------------------
extern "C" void kernel_launch(void* const* d_in, const int* in_sizes, int n_in,
                              void* d_out, int out_size, void* d_ws, size_t ws_size,
                              hipStream_t stream) {
    const float* query = (const float*)d_in[0];
    const float* key   = (const float*)d_in[1];
    const float* value = (const float*)d_in[2];
    const float* wg    = (const float*)d_in[3];
    const float* wmap  = (const float*)d_in[4];
    const float* wred  = (const float*)d_in[5];
    const float* wk    = (const float*)d_in[6];
    const float* wv    = (const float*)d_in[7];
    const float* rpe   = (const float*)d_in[8];
    float* out = (float*)d_out;

    char* ws = (char*)d_ws;
    float*  gates = (float*)(ws + 0);                      // 32 KB
    int*    idx   = (int*)(ws + (32 << 10));               // 32 KB
    char*   misc  = ws + (64 << 10);
    int*    counts = (int*)(misc + 0);                     // [zeroed]
    int*    cur    = (int*)(misc + 64);                    // [zeroed]
    int*    offs   = (int*)(misc + 128);
    int*    rbe2   = (int*)(misc + 8192);
    int*    rbs2   = (int*)(misc + 9472);
    int*    rbc2   = (int*)(misc + 10752);
    int*    perm  = (int*)(ws + (96 << 10));               // 32 KB
    char*   base  = ws + (128 << 10);
    float*  qp    = (float*)(base);                        // 8 MB f32 (rel input)
    ushort* qpb   = (ushort*)(base + (8u  << 20));         // 4 MB
    ushort* kpb   = (ushort*)(base + (12u << 20));         // 1 MB [b][t][ed]
    ushort* vpT   = (ushort*)(base + (13u << 20));         // 1 MB [b][h][d][t]
    ushort* xb    = (ushort*)(base + (14u << 20));         // 4 MB  (dead before reduce)
    ushort* wmapT = (ushort*)(base + (18u << 20));         // 6 MB  (dead before reduce)
    ushort* keyb  = (ushort*)(base + (24u << 20));         // 4 MB  (dead before reduce)
    ushort* valb  = (ushort*)(base + (28u << 20));         // 4 MB  (dead before reduce)
    ushort* wkT   = (ushort*)(base + (32u << 20));         // 0.5 MB
    ushort* wvT   = (ushort*)(base + (32u << 20) + (512u << 10)); // 0.5 MB
    float*  z4    = (float*)(base + (14u << 20));          // 33.5 MB, overlaps xb..wvT (dead)
    ushort* azd   = (ushort*)(base + (48u << 20));         // 12.6 MB [row][768]
    ushort* wredT3= (ushort*)(base + (61u << 20));         // 18.9 MB [e][d][768]
    float*  rel   = (float*)(base + (80u << 20));          // 16 MB
    float*  wgT   = (float*)(base + (96u << 20));          // 48 KB f32 [e][d]

    hipMemsetAsync(misc, 0, 128, stream);

    castwg_kernel<<<D_ / 256, 256, 0, stream>>>(wg, wgT);
    castx_kernel<<<(N_ * D_) / 1024, 256, 0, stream>>>(query, xb);
    castx_kernel<<<(N_ * D_) / 1024, 256, 0, stream>>>(key, keyb);
    castx_kernel<<<(N_ * D_) / 1024, 256, 0, stream>>>(value, valb);
    castw_kernel<<<dim3(E_, 16, 4), 256, 0, stream>>>(wmap, wmapT);
    castwkv_kernel<<<dim3(2, 16, 4), 256, 0, stream>>>(wk, wv, wkT, wvT);
    castwred_kernel<<<dim3(E_, 4, 16), 256, 0, stream>>>(wred, wredT3);
    gate_kernel<<<N_ / 4, 256, 0, stream>>>(query, wgT, gates, idx, counts);
    scan_kernel<<<1, 64, 0, stream>>>(counts, offs, rbe2, rbs2, rbc2);
    scatter_kernel<<<NROW / 256, 256, 0, stream>>>(idx, offs, cur, perm);
    kv_mfma<<<dim3(64, 2), 256, 0, stream>>>(keyb, valb, wkT, wvT, kpb, vpT);
    qproj_mfma<<<PB_MAX, 256, 0, stream>>>(xb, wmapT, perm, rbe2, rbs2, rbc2, qp, qpb);
    rel_kernel<<<(32 * T_) / 2, 256, 0, stream>>>(qp, rpe, rel);
    attn_kernel<<<512, 256, 0, stream>>>(qpb, kpb, vpT, rel, gates, azd);
    reduce_mfma<<<dim3(PB_MAX, 4), 256, 0, stream>>>(azd, wredT3, perm, rbe2, rbs2, rbc2, z4);
    combine_out<<<(N_ * D_) / 1024, 256, 0, stream>>>(z4, out);
}

// Round 7
// 314.491 us; speedup vs baseline: 1.3349x; 1.3349x over previous
//
#include <hip/hip_runtime.h>

#define T_    1024
#define B_    2
#define D_    1024
#define E_    12
#define TOPK  4
#define ED_   256
#define HD_   64
#define H_    4
#define N_    (T_*B_)      // 2048 tokens
#define NROW  (N_*TOPK)    // 8192 (n,k) rows
#define PB_MAX 268         // max 32-row expert chunks: 8192/32 + 12
#define KR_   768          // split-precision K for reduce: [a_hi|a_lo|a_hi]

typedef __bf16 bf16x8 __attribute__((ext_vector_type(8)));
typedef float  f32x4  __attribute__((ext_vector_type(4)));

__device__ __forceinline__ float sc_() { return 0.35355339059327373f; } // 64^-0.25

__device__ __forceinline__ void async16(const void* g, void* l) {
    __builtin_amdgcn_global_load_lds((const __attribute__((address_space(1))) void*)g,
                                     (__attribute__((address_space(3))) void*)l, 16, 0, 0);
}

// ---------------- one-time: wgT[e][d] = wg[d][e] (f32, 48 KB) ----------------
__global__ void castwg_kernel(const float* __restrict__ wg, float* __restrict__ wgT) {
    int d = blockIdx.x * 256 + threadIdx.x;   // grid 4 x 256
#pragma unroll
    for (int e = 0; e < E_; ++e) wgT[e * D_ + d] = wg[d * E_ + e];
}

// ---------------- gating: wave per token, NO atomics -------------------------
__global__ void __launch_bounds__(256)
gate_kernel(const float* __restrict__ x, const float* __restrict__ wgT,
            float* __restrict__ gates, int* __restrict__ idx) {
    int w = threadIdx.x >> 6, L = threadIdx.x & 63;
    int n = blockIdx.x * 4 + w;
    const float* xr = x + (size_t)n * D_;
    float acc[E_];
#pragma unroll
    for (int e = 0; e < E_; ++e) acc[e] = 0.f;
#pragma unroll
    for (int it = 0; it < 4; ++it) {
        float4 xv = *(const float4*)(xr + it * 256 + L * 4);
#pragma unroll
        for (int e = 0; e < E_; ++e) {
            float4 wv = *(const float4*)(wgT + e * D_ + it * 256 + L * 4);
            acc[e] += xv.x * wv.x + xv.y * wv.y + xv.z * wv.z + xv.w * wv.w;
        }
    }
#pragma unroll
    for (int e = 0; e < E_; ++e) {
        float v = acc[e];
        for (int o = 32; o > 0; o >>= 1) v += __shfl_down(v, o);
        acc[e] = v;
    }
    if (L == 0) {
        float mx = acc[0];
        for (int e = 1; e < E_; ++e) mx = fmaxf(mx, acc[e]);
        float s = 0.f, pr[E_];
        for (int e = 0; e < E_; ++e) { pr[e] = expf(acc[e] - mx); s += pr[e]; }
        float inv = 1.f / s;
        for (int e = 0; e < E_; ++e) pr[e] *= inv;
        for (int k = 0; k < TOPK; ++k) {
            int be = 0; float bv = -1.f;
            for (int e = 0; e < E_; ++e) if (pr[e] > bv) { bv = pr[e]; be = e; }
            gates[n * TOPK + k] = bv;
            idx[n * TOPK + k] = be;
            pr[be] = -1.f;
        }
    }
}

// ---------------- hist: per-block expert counts via ballot (no atomics) ------
// grid 32, block 256: block b covers rows b*256..+255
__global__ void hist_kernel(const int* __restrict__ idx, int* __restrict__ bcnt) {
    int b = blockIdx.x, tid = threadIdx.x, w = tid >> 6, L = tid & 63;
    int e = idx[b * 256 + tid];
    __shared__ int wcnt[4][E_];
#pragma unroll
    for (int e0 = 0; e0 < E_; ++e0) {
        unsigned long long m = __ballot(e == e0);
        if (L == 0) wcnt[w][e0] = (int)__popcll(m);
    }
    __syncthreads();
    if (tid < E_) bcnt[b * E_ + tid] = wcnt[0][tid] + wcnt[1][tid] + wcnt[2][tid] + wcnt[3][tid];
}

// ---------------- scan: offsets + per-block bases + 32-row chunk map ---------
__global__ void scan_kernel(const int* __restrict__ bcnt, int* __restrict__ offs,
                            int* __restrict__ base,
                            int* __restrict__ rbe2, int* __restrict__ rbs2,
                            int* __restrict__ rbc2) {
    if (threadIdx.x == 0 && blockIdx.x == 0) {
        int counts[E_], offl[E_ + 1];
        for (int e = 0; e < E_; ++e) {
            int s = 0;
            for (int b = 0; b < 32; ++b) s += bcnt[b * E_ + e];
            counts[e] = s;
        }
        int o = 0;
        for (int e = 0; e < E_; ++e) { offl[e] = o; o += counts[e]; }
        offl[E_] = o;
        for (int e = 0; e <= E_; ++e) offs[e] = offl[e];
        for (int e = 0; e < E_; ++e) {
            int run = offl[e];
            for (int b = 0; b < 32; ++b) { base[b * E_ + e] = run; run += bcnt[b * E_ + e]; }
        }
        int nb2 = 0;
        for (int e = 0; e < E_; ++e) {
            int c = counts[e];
            for (int s = 0; s < c; s += 32) {
                rbe2[nb2] = e; rbs2[nb2] = offl[e] + s;
                rbc2[nb2] = (c - s < 32) ? (c - s) : 32; ++nb2;
            }
        }
        for (; nb2 < PB_MAX; ++nb2) { rbe2[nb2] = 0; rbs2[nb2] = 0; rbc2[nb2] = 0; }
    }
}

// ---------------- scatter via ballot rank (no atomics) -----------------------
__global__ void scatter_kernel(const int* __restrict__ idx, const int* __restrict__ base,
                               int* __restrict__ perm) {
    int b = blockIdx.x, tid = threadIdx.x, w = tid >> 6, L = tid & 63;
    int r = b * 256 + tid;
    int e = idx[r];
    __shared__ int wcnt[4][E_];
    int rankw = 0;
#pragma unroll
    for (int e0 = 0; e0 < E_; ++e0) {
        unsigned long long m = __ballot(e == e0);
        if (e == e0) rankw = (int)__popcll(m & ((1ULL << L) - 1ULL));
        if (L == 0) wcnt[w][e0] = (int)__popcll(m);
    }
    __syncthreads();
    int pre = 0;
    for (int w2 = 0; w2 < w; ++w2) pre += wcnt[w2][e];
    perm[base[b * E_ + e] + pre + rankw] = r;
}

// ---------------- one-time casts ---------------------------------------------
__global__ void castx_kernel(const float* __restrict__ x, ushort* __restrict__ xb) {
    int t = blockIdx.x * 256 + threadIdx.x;
    float4 v = *(const float4*)(x + (size_t)t * 4);
    union { __bf16 h[4]; uint2 u; } pk;
    pk.h[0] = (__bf16)v.x; pk.h[1] = (__bf16)v.y;
    pk.h[2] = (__bf16)v.z; pk.h[3] = (__bf16)v.w;
    *(uint2*)(xb + (size_t)t * 4) = pk.u;
}

// grid (12,16,4): e, 64-d tile, 64-ed tile.  wmapT[e][ed][d] = bf16(w_map[e][d][ed])
__global__ void castw_kernel(const float* __restrict__ wmap, ushort* __restrict__ wmapT) {
    int e = blockIdx.x, dt = blockIdx.y, et = blockIdx.z;
    __shared__ float ls[64][65];
    int c = threadIdx.x & 63, rg = threadIdx.x >> 6;
    const float* src = wmap + (size_t)e * (D_ * ED_) + (size_t)(dt * 64) * ED_ + et * 64;
#pragma unroll
    for (int q = 0; q < 16; ++q) {
        int r = q * 4 + rg;
        ls[r][c] = src[(size_t)r * ED_ + c];
    }
    __syncthreads();
    ushort* dst = wmapT + ((size_t)e << 18) + (size_t)(et * 64) * 1024 + dt * 64;
#pragma unroll
    for (int q = 0; q < 16; ++q) {
        int r = q * 4 + rg;
        union { __bf16 h; ushort u; } cv; cv.h = (__bf16)ls[c][r];
        dst[(size_t)r * 1024 + c] = cv.u;
    }
}

// grid (2,16,4): which, 64-d tile, 64-ed tile. wT[ed][d] = bf16(w[d][ed])
__global__ void castwkv_kernel(const float* __restrict__ wk, const float* __restrict__ wv,
                               ushort* __restrict__ wkT, ushort* __restrict__ wvT) {
    int which = blockIdx.x, dt = blockIdx.y, et = blockIdx.z;
    const float* w = which ? wv : wk;
    ushort* wT = which ? wvT : wkT;
    __shared__ float ls[64][65];
    int c = threadIdx.x & 63, rg = threadIdx.x >> 6;
    const float* src = w + (size_t)(dt * 64) * ED_ + et * 64;
#pragma unroll
    for (int q = 0; q < 16; ++q) {
        int r = q * 4 + rg;
        ls[r][c] = src[(size_t)r * ED_ + c];
    }
    __syncthreads();
    ushort* dst = wT + (size_t)(et * 64) * 1024 + dt * 64;
#pragma unroll
    for (int q = 0; q < 16; ++q) {
        int r = q * 4 + rg;
        union { __bf16 h; ushort u; } cv; cv.h = (__bf16)ls[c][r];
        dst[(size_t)r * 1024 + c] = cv.u;
    }
}

// grid (12,4,16): e, 64-ed tile, 64-d tile.
// wredT3[e][d][k]: k in [0,256)=w_hi[ed], [256,512)=w_hi[ed], [512,768)=w_lo[ed]
__global__ void castwred_kernel(const float* __restrict__ wred, ushort* __restrict__ wredT3) {
    int e = blockIdx.x, et = blockIdx.y, dt = blockIdx.z;
    __shared__ float ls[64][65];
    int c = threadIdx.x & 63, rg = threadIdx.x >> 6;
    const float* src = wred + (size_t)e * (ED_ * D_) + (size_t)(et * 64) * D_ + dt * 64;
#pragma unroll
    for (int q = 0; q < 16; ++q) {
        int r = q * 4 + rg;           // ed-local
        ls[r][c] = src[(size_t)r * D_ + c];
    }
    __syncthreads();
    ushort* dst = wredT3 + (size_t)e * (D_ * KR_) + (size_t)(dt * 64) * KR_ + et * 64;
#pragma unroll
    for (int q = 0; q < 16; ++q) {
        int r = q * 4 + rg;           // d-local
        float v = ls[c][r];
        union { __bf16 h; ushort u; } hi; hi.h = (__bf16)v;
        float lo = v - (float)hi.h;
        union { __bf16 h; ushort u; } lov; lov.h = (__bf16)lo;
        dst[(size_t)r * KR_ + c] = hi.u;
        dst[(size_t)r * KR_ + 256 + c] = hi.u;
        dst[(size_t)r * KR_ + 512 + c] = lov.u;
    }
}

// ---------------- k/v projection as bf16 MFMA GEMM ---------------------------
__global__ void __launch_bounds__(256)
kv_mfma(const ushort* __restrict__ keyb, const ushort* __restrict__ valb,
        const ushort* __restrict__ wkT, const ushort* __restrict__ wvT,
        ushort* __restrict__ kpb, ushort* __restrict__ vpT) {
    int which = blockIdx.y;
    const ushort* xb = which ? valb : keyb;
    const ushort* wT = which ? wvT : wkT;
    int m0 = blockIdx.x * 32;
    int b = m0 >> 10, t0 = m0 & 1023;
    int tid = threadIdx.x, w = tid >> 6, L = tid & 63;
    __shared__ __align__(16) ushort As[2][32 * 64];
    __shared__ __align__(16) ushort Bs[2][4 * 64 * 64];

    int swz = ((L & 7) ^ ((L >> 3) & 7)) * 8;
    int an = (((t0 + w * 8 + (L >> 3)) << 1) | b);
    const ushort* asrc = xb + (size_t)an * 1024 + swz;
    const ushort* bsrc = wT + (size_t)(w * 64 + (L >> 3)) * 1024 + swz;

    f32x4 acc[2][4];
#pragma unroll
    for (int mt = 0; mt < 2; ++mt)
#pragma unroll
        for (int nt = 0; nt < 4; ++nt) acc[mt][nt] = (f32x4){0.f, 0.f, 0.f, 0.f};

    auto stage = [&](int kt, int bf) {
        async16(asrc + kt * 64, &As[bf][w * 512]);
#pragma unroll
        for (int q = 0; q < 8; ++q)
            async16(bsrc + (size_t)q * 8192 + kt * 64, &Bs[bf][(w * 64 + q * 8) * 64]);
    };
    auto compute = [&](int bf) {
        const ushort* AB = As[bf];
        const ushort* BB = Bs[bf] + w * 4096;
#pragma unroll
        for (int ks = 0; ks < 2; ++ks) {
            int phys = (((ks * 4 + (L >> 4)) ^ (L & 7))) * 8;
            bf16x8 a0 = *(const bf16x8*)(AB + (L & 15) * 64 + phys);
            bf16x8 a1 = *(const bf16x8*)(AB + (16 + (L & 15)) * 64 + phys);
#pragma unroll
            for (int nt = 0; nt < 4; ++nt) {
                bf16x8 bfr = *(const bf16x8*)(BB + (nt * 16 + (L & 15)) * 64 + phys);
                acc[0][nt] = __builtin_amdgcn_mfma_f32_16x16x32_bf16(a0, bfr, acc[0][nt], 0, 0, 0);
                acc[1][nt] = __builtin_amdgcn_mfma_f32_16x16x32_bf16(a1, bfr, acc[1][nt], 0, 0, 0);
            }
        }
    };

    stage(0, 0);
    for (int t = 0; t < 16; ++t) {
        __syncthreads();
        if (t < 15) stage(t + 1, (t + 1) & 1);
        compute(t & 1);
    }

#pragma unroll
    for (int mt = 0; mt < 2; ++mt)
#pragma unroll
        for (int nt = 0; nt < 4; ++nt) {
            int ed = w * 64 + nt * 16 + (L & 15);
            int tb = t0 + mt * 16 + (L >> 4) * 4;
            if (which == 0) {
#pragma unroll
                for (int r = 0; r < 4; ++r) {
                    union { __bf16 h; ushort u; } cv;
                    cv.h = (__bf16)(acc[mt][nt][r] * sc_());
                    kpb[((size_t)((b << 10) + tb + r)) * ED_ + ed] = cv.u;
                }
            } else {
                int h = ed >> 6, d = ed & 63;
                union { __bf16 h4[4]; uint2 u; } pk;
#pragma unroll
                for (int r = 0; r < 4; ++r) pk.h4[r] = (__bf16)acc[mt][nt][r];
                *(uint2*)&vpT[((size_t)((b * 4 + h) * 64 + d)) * 1024 + tb] = pk.u;
            }
        }
}

// ---------------- q projection as bf16 MFMA GEMM per 32-row expert chunk -----
__global__ void __launch_bounds__(256)
qproj_mfma(const ushort* __restrict__ xb, const ushort* __restrict__ wmapT,
           const int* __restrict__ perm,
           const int* __restrict__ rbe2, const int* __restrict__ rbs2,
           const int* __restrict__ rbc2,
           float* __restrict__ qp, ushort* __restrict__ qpb) {
    int blk = blockIdx.x;
    int nr = rbc2[blk];
    if (nr == 0) return;
    int e = rbe2[blk], rs = rbs2[blk];
    int tid = threadIdx.x, w = tid >> 6, L = tid & 63;
    __shared__ __align__(16) ushort As[2][32 * 64];
    __shared__ __align__(16) ushort Bs[2][4 * 64 * 64];
    __shared__ int rows2[32];
    if (tid < 32) rows2[tid] = (tid < nr) ? perm[rs + tid] : -1;
    __syncthreads();

    int swz = ((L & 7) ^ ((L >> 3) & 7)) * 8;
    int ar = rows2[w * 8 + (L >> 3)];
    const ushort* asrc = xb + (size_t)((ar < 0 ? 0 : ar) >> 2) * 1024 + swz;
    const ushort* bsrc = wmapT + ((size_t)e << 18) + (size_t)(w * 64 + (L >> 3)) * 1024 + swz;

    f32x4 acc[2][4];
#pragma unroll
    for (int mt = 0; mt < 2; ++mt)
#pragma unroll
        for (int nt = 0; nt < 4; ++nt) acc[mt][nt] = (f32x4){0.f, 0.f, 0.f, 0.f};

    auto stage = [&](int kt, int bf) {
        async16(asrc + kt * 64, &As[bf][w * 512]);
#pragma unroll
        for (int q = 0; q < 8; ++q)
            async16(bsrc + (size_t)q * 8192 + kt * 64, &Bs[bf][(w * 64 + q * 8) * 64]);
    };
    auto compute = [&](int bf) {
        const ushort* AB = As[bf];
        const ushort* BB = Bs[bf] + w * 4096;
#pragma unroll
        for (int ks = 0; ks < 2; ++ks) {
            int phys = (((ks * 4 + (L >> 4)) ^ (L & 7))) * 8;
            bf16x8 a0 = *(const bf16x8*)(AB + (L & 15) * 64 + phys);
            bf16x8 a1 = *(const bf16x8*)(AB + (16 + (L & 15)) * 64 + phys);
#pragma unroll
            for (int nt = 0; nt < 4; ++nt) {
                bf16x8 b = *(const bf16x8*)(BB + (nt * 16 + (L & 15)) * 64 + phys);
                acc[0][nt] = __builtin_amdgcn_mfma_f32_16x16x32_bf16(a0, b, acc[0][nt], 0, 0, 0);
                acc[1][nt] = __builtin_amdgcn_mfma_f32_16x16x32_bf16(a1, b, acc[1][nt], 0, 0, 0);
            }
        }
    };

    stage(0, 0);
    for (int t = 0; t < 16; ++t) {
        __syncthreads();
        if (t < 15) stage(t + 1, (t + 1) & 1);
        compute(t & 1);
    }

#pragma unroll
    for (int mt = 0; mt < 2; ++mt)
#pragma unroll
        for (int nt = 0; nt < 4; ++nt) {
            int n = w * 64 + nt * 16 + (L & 15);
#pragma unroll
            for (int r = 0; r < 4; ++r) {
                int m = mt * 16 + (L >> 4) * 4 + r;
                int rowg = rows2[m];
                if (rowg >= 0) {
                    float v = acc[mt][nt][r] * sc_();
                    qp[(size_t)rowg * ED_ + n] = v;
                    union { __bf16 h; ushort u; } cv; cv.h = (__bf16)v;
                    qpb[(size_t)rowg * ED_ + n] = cv.u;
                }
            }
        }
}

// ---------------- rel bias table: rel[bkh,i,p] = q_row . rpe[h,:,p] ----------
__global__ void rel_kernel(const float* __restrict__ qp, const float* __restrict__ rpe,
                           float* __restrict__ rel) {
    int Rr = blockIdx.x * 2 + (threadIdx.x >> 7);
    int p = threadIdx.x & 127;
    int i = Rr & 1023, h = (Rr >> 10) & 3, kk = (Rr >> 12) & 3, bb = Rr >> 14;
    int row = ((i * 2 + bb) << 2) | kk;
    int qbase = __builtin_amdgcn_readfirstlane(row * ED_ + h * HD_);
    int hbase = __builtin_amdgcn_readfirstlane(h * HD_);
    float acc = 0.f;
    for (int d = 0; d < HD_; ++d)
        acc += qp[qbase + d] * rpe[(hbase + d) * 129 + p];
    rel[Rr * 128 + p] = acc;
}

// ---------------- MFMA flash attention (bf16, no-max softmax) ----------------
// epilogue writes split-precision azd[row][768] = [a_hi | a_lo | a_hi] (bf16)
__global__ void __launch_bounds__(256)
attn_kernel(const ushort* __restrict__ qpb, const ushort* __restrict__ kpb,
            const ushort* __restrict__ vpT, const float* __restrict__ rel,
            const float* __restrict__ gates, ushort* __restrict__ azd) {
    __shared__ __align__(16) ushort Ks[2][64 * 64];
    __shared__ __align__(16) ushort Vs[2][64 * 64];
    __shared__ __align__(16) ushort Ps[4][16 * 64];

    const int tid = threadIdx.x;
    const int w = tid >> 6, L = tid & 63;
    const int bkh = blockIdx.x & 31, it = blockIdx.x >> 5;
    const int h = bkh & 3, kk = (bkh >> 2) & 3, bb = bkh >> 4;
    const int i0w = it * 64 + w * 16;
    const int iL = i0w + (L & 15);
    const int row = ((iL * 2 + bb) << 2) | kk;

    const ushort* qrow = qpb + row * ED_ + h * HD_;
    bf16x8 qf0 = *(const bf16x8*)(qrow + (L >> 4) * 8);
    bf16x8 qf1 = *(const bf16x8*)(qrow + 32 + (L >> 4) * 8);

    const float* relrow = rel + ((size_t)((bkh << 10) + iL)) * 128;
    float rel_lo = relrow[1], rel_hi = relrow[127];
    float gate = gates[row];

    f32x4 O[4];
#pragma unroll
    for (int mf = 0; mf < 4; ++mf) O[mf] = (f32x4){0.f, 0.f, 0.f, 0.f};
    float l_acc = 0.f;

    const ushort* ksrc = kpb + (size_t)(bb << 10) * ED_ + h * HD_;
    const ushort* vsrc = vpT + (size_t)((bb * 4 + h) * 64) * 1024;

    auto stage = [&](int t, int bf) {
        int j0 = t * 64;
#pragma unroll
        for (int q = 0; q < 2; ++q) {
            int r = L >> 3;
            int c = (L & 7) ^ r;
            const ushort* src = ksrc + (size_t)(j0 + w * 16 + q * 8 + r) * ED_ + c * 8;
            async16(src, &Ks[bf][(w * 16 + q * 8) * 64]);
        }
#pragma unroll
        for (int q = 0; q < 2; ++q) {
            int r = L >> 3;
            int d = w * 16 + q * 8 + r;
            int c = (L & 7) ^ (d & 7);
            const ushort* src = vsrc + (size_t)d * 1024 + j0 + c * 8;
            async16(src, &Vs[bf][(w * 16 + q * 8) * 64]);
        }
    };

    auto compute = [&](int bf, int j0) {
        const ushort* KB = Ks[bf];
        const ushort* VB = Vs[bf];
        ushort* PW = Ps[w];
#pragma unroll
        for (int jf = 0; jf < 4; ++jf) {
            int jrow = jf * 16 + (L & 15);
            bf16x8 a0 = *(const bf16x8*)(KB + jrow * 64 + (((L >> 4)) ^ (L & 7)) * 8);
            bf16x8 a1 = *(const bf16x8*)(KB + jrow * 64 + ((4 + (L >> 4)) ^ (L & 7)) * 8);
            f32x4 s = (f32x4){0.f, 0.f, 0.f, 0.f};
            s = __builtin_amdgcn_mfma_f32_16x16x32_bf16(a0, qf0, s, 0, 0, 0);
            s = __builtin_amdgcn_mfma_f32_16x16x32_bf16(a1, qf1, s, 0, 0, 0);
            int jlo = j0 + jf * 16;
            int jbase = jlo + (L >> 4) * 4;
            float pv[4];
            if (jlo >= i0w + 78) {
#pragma unroll
                for (int r = 0; r < 4; ++r) pv[r] = __expf(s[r] + rel_hi);
            } else if (jlo <= i0w - 78) {
#pragma unroll
                for (int r = 0; r < 4; ++r) pv[r] = __expf(s[r] + rel_lo);
            } else {
#pragma unroll
                for (int r = 0; r < 4; ++r) {
                    int dj = jbase + r - iL;
                    dj = dj < -63 ? -63 : (dj > 63 ? 63 : dj);
                    pv[r] = __expf(s[r] + relrow[dj + 64]);
                }
            }
            l_acc += (pv[0] + pv[1]) + (pv[2] + pv[3]);
            union { __bf16 h4[4]; uint2 u; } pk;
#pragma unroll
            for (int r = 0; r < 4; ++r) pk.h4[r] = (__bf16)pv[r];
            int iloc = L & 15;
            int chunk = jf * 2 + ((L >> 4) >> 1);
            int phys = chunk ^ (iloc & 7);
            *(uint2*)(PW + iloc * 64 + phys * 8 + ((L >> 4) & 1) * 4) = pk.u;
        }
#pragma unroll
        for (int ks = 0; ks < 2; ++ks) {
            int c = ks * 4 + (L >> 4);
            int phys = c ^ (L & 7);
            bf16x8 pf = *(const bf16x8*)(PW + (L & 15) * 64 + phys * 8);
#pragma unroll
            for (int mf = 0; mf < 4; ++mf) {
                bf16x8 vf = *(const bf16x8*)(VB + (mf * 16 + (L & 15)) * 64 + phys * 8);
                O[mf] = __builtin_amdgcn_mfma_f32_16x16x32_bf16(vf, pf, O[mf], 0, 0, 0);
            }
        }
    };

    stage(0, 0);
    for (int t = 0; t < 16; ++t) {
        __syncthreads();
        if (t < 15) stage(t + 1, (t + 1) & 1);
        compute(t & 1, t * 64);
    }

    l_acc += __shfl_xor(l_acc, 16);
    l_acc += __shfl_xor(l_acc, 32);
    float inv = gate / l_acc;
    ushort* azrow = azd + (size_t)row * KR_ + h * HD_;
#pragma unroll
    for (int mf = 0; mf < 4; ++mf) {
        union { __bf16 h4[4]; uint2 u; } hi, lo;
#pragma unroll
        for (int r = 0; r < 4; ++r) {
            float v = O[mf][r] * inv;
            hi.h4[r] = (__bf16)v;
            lo.h4[r] = (__bf16)(v - (float)hi.h4[r]);
        }
        int off = mf * 16 + (L >> 4) * 4;
        *(uint2*)(azrow + off) = hi.u;
        *(uint2*)(azrow + 256 + off) = lo.u;
        *(uint2*)(azrow + 512 + off) = hi.u;
    }
}

// ---------------- expert reduce as bf16 MFMA (split precision, K=768) --------
__global__ void __launch_bounds__(256)
reduce_mfma(const ushort* __restrict__ azd, const ushort* __restrict__ wredT3,
            const int* __restrict__ perm,
            const int* __restrict__ rbe2, const int* __restrict__ rbs2,
            const int* __restrict__ rbc2, float* __restrict__ z4) {
    int blk = blockIdx.x;
    int nr = rbc2[blk];
    if (nr == 0) return;
    int e = rbe2[blk], rs = rbs2[blk];
    int n0 = blockIdx.y * 256;
    int tid = threadIdx.x, w = tid >> 6, L = tid & 63;
    __shared__ __align__(16) ushort As[2][32 * 64];
    __shared__ __align__(16) ushort Bs[2][4 * 64 * 64];
    __shared__ int rows2[32];
    if (tid < 32) rows2[tid] = (tid < nr) ? perm[rs + tid] : -1;
    __syncthreads();

    int swz = ((L & 7) ^ ((L >> 3) & 7)) * 8;
    int ar = rows2[w * 8 + (L >> 3)];
    const ushort* asrc = azd + (size_t)(ar < 0 ? 0 : ar) * KR_ + swz;
    const ushort* bsrc = wredT3 + (size_t)e * (D_ * KR_)
                       + (size_t)(n0 + w * 64 + (L >> 3)) * KR_ + swz;

    f32x4 acc[2][4];
#pragma unroll
    for (int mt = 0; mt < 2; ++mt)
#pragma unroll
        for (int nt = 0; nt < 4; ++nt) acc[mt][nt] = (f32x4){0.f, 0.f, 0.f, 0.f};

    auto stage = [&](int kt, int bf) {
        async16(asrc + kt * 64, &As[bf][w * 512]);
#pragma unroll
        for (int q = 0; q < 8; ++q)
            async16(bsrc + (size_t)q * (8 * KR_) + kt * 64, &Bs[bf][(w * 64 + q * 8) * 64]);
    };
    auto compute = [&](int bf) {
        const ushort* AB = As[bf];
        const ushort* BB = Bs[bf] + w * 4096;
#pragma unroll
        for (int ks = 0; ks < 2; ++ks) {
            int phys = (((ks * 4 + (L >> 4)) ^ (L & 7))) * 8;
            bf16x8 a0 = *(const bf16x8*)(AB + (L & 15) * 64 + phys);
            bf16x8 a1 = *(const bf16x8*)(AB + (16 + (L & 15)) * 64 + phys);
#pragma unroll
            for (int nt = 0; nt < 4; ++nt) {
                bf16x8 b = *(const bf16x8*)(BB + (nt * 16 + (L & 15)) * 64 + phys);
                acc[0][nt] = __builtin_amdgcn_mfma_f32_16x16x32_bf16(a0, b, acc[0][nt], 0, 0, 0);
                acc[1][nt] = __builtin_amdgcn_mfma_f32_16x16x32_bf16(a1, b, acc[1][nt], 0, 0, 0);
            }
        }
    };

    stage(0, 0);
    for (int t = 0; t < 12; ++t) {       // K = 768 -> 12 tiles of 64
        __syncthreads();
        if (t < 11) stage(t + 1, (t + 1) & 1);
        compute(t & 1);
    }

#pragma unroll
    for (int mt = 0; mt < 2; ++mt)
#pragma unroll
        for (int nt = 0; nt < 4; ++nt) {
            int n = n0 + w * 64 + nt * 16 + (L & 15);
#pragma unroll
            for (int r = 0; r < 4; ++r) {
                int m = mt * 16 + (L >> 4) * 4 + r;
                int rowg = rows2[m];
                if (rowg >= 0) z4[(size_t)rowg * D_ + n] = acc[mt][nt][r];
            }
        }
}

// ---------------- combine: out[n] = sum_k z4[n*4+k] --------------------------
__global__ void combine_out(const float* __restrict__ z4, float* __restrict__ out) {
    int t = blockIdx.x * 256 + threadIdx.x;     // N_*D_/4 threads
    int n = t >> 8, d0 = (t & 255) * 4;
    const float* zr = z4 + (size_t)(n * 4) * D_ + d0;
    float4 a = *(const float4*)(zr);
    float4 b = *(const float4*)(zr + D_);
    float4 c = *(const float4*)(zr + 2 * D_);
    float4 d = *(const float4*)(zr + 3 * D_);
    float4 s = make_float4(a.x + b.x + c.x + d.x, a.y + b.y + c.y + d.y,
                           a.z + b.z + c.z + d.z, a.w + b.w + c.w + d.w);
    *(float4*)(out + (size_t)n * D_ + d0) = s;
}

// ---------------- launcher ---------------------------------------------------
extern "C" void kernel_launch(void* const* d_in, const int* in_sizes, int n_in,
                              void* d_out, int out_size, void* d_ws, size_t ws_size,
                              hipStream_t stream) {
    const float* query = (const float*)d_in[0];
    const float* key   = (const float*)d_in[1];
    const float* value = (const float*)d_in[2];
    const float* wg    = (const float*)d_in[3];
    const float* wmap  = (const float*)d_in[4];
    const float* wred  = (const float*)d_in[5];
    const float* wk    = (const float*)d_in[6];
    const float* wv    = (const float*)d_in[7];
    const float* rpe   = (const float*)d_in[8];
    float* out = (float*)d_out;

    char* ws = (char*)d_ws;
    float*  gates = (float*)(ws + 0);                      // 32 KB
    int*    idx   = (int*)(ws + (32 << 10));               // 32 KB
    char*   misc  = ws + (64 << 10);
    int*    offs   = (int*)(misc + 128);                   // 13 ints
    int*    bcnt   = (int*)(misc + 1024);                  // 32*12 ints
    int*    base   = (int*)(misc + 3072);                  // 32*12 ints
    int*    rbe2   = (int*)(misc + 8192);
    int*    rbs2   = (int*)(misc + 9472);
    int*    rbc2   = (int*)(misc + 10752);
    int*    perm  = (int*)(ws + (96 << 10));               // 32 KB
    char*   base_ = ws + (128 << 10);
    float*  qp    = (float*)(base_);                       // 8 MB f32 (rel input)
    ushort* qpb   = (ushort*)(base_ + (8u  << 20));        // 4 MB
    ushort* kpb   = (ushort*)(base_ + (12u << 20));        // 1 MB [b][t][ed]
    ushort* vpT   = (ushort*)(base_ + (13u << 20));        // 1 MB [b][h][d][t]
    ushort* xb    = (ushort*)(base_ + (14u << 20));        // 4 MB  (dead before reduce)
    ushort* wmapT = (ushort*)(base_ + (18u << 20));        // 6 MB  (dead before reduce)
    ushort* keyb  = (ushort*)(base_ + (24u << 20));        // 4 MB  (dead before reduce)
    ushort* valb  = (ushort*)(base_ + (28u << 20));        // 4 MB  (dead before reduce)
    ushort* wkT   = (ushort*)(base_ + (32u << 20));        // 0.5 MB
    ushort* wvT   = (ushort*)(base_ + (32u << 20) + (512u << 10)); // 0.5 MB
    float*  z4    = (float*)(base_ + (14u << 20));         // 33.5 MB, overlaps xb..wvT (dead)
    ushort* azd   = (ushort*)(base_ + (48u << 20));        // 12.6 MB [row][768]
    ushort* wredT3= (ushort*)(base_ + (61u << 20));        // 18.9 MB [e][d][768]
    float*  rel   = (float*)(base_ + (80u << 20));         // 16 MB
    float*  wgT   = (float*)(base_ + (96u << 20));         // 48 KB f32 [e][d]

    castwg_kernel<<<D_ / 256, 256, 0, stream>>>(wg, wgT);
    castx_kernel<<<(N_ * D_) / 1024, 256, 0, stream>>>(query, xb);
    castx_kernel<<<(N_ * D_) / 1024, 256, 0, stream>>>(key, keyb);
    castx_kernel<<<(N_ * D_) / 1024, 256, 0, stream>>>(value, valb);
    castw_kernel<<<dim3(E_, 16, 4), 256, 0, stream>>>(wmap, wmapT);
    castwkv_kernel<<<dim3(2, 16, 4), 256, 0, stream>>>(wk, wv, wkT, wvT);
    castwred_kernel<<<dim3(E_, 4, 16), 256, 0, stream>>>(wred, wredT3);
    gate_kernel<<<N_ / 4, 256, 0, stream>>>(query, wgT, gates, idx);
    hist_kernel<<<NROW / 256, 256, 0, stream>>>(idx, bcnt);
    scan_kernel<<<1, 64, 0, stream>>>(bcnt, offs, base, rbe2, rbs2, rbc2);
    scatter_kernel<<<NROW / 256, 256, 0, stream>>>(idx, base, perm);
    kv_mfma<<<dim3(64, 2), 256, 0, stream>>>(keyb, valb, wkT, wvT, kpb, vpT);
    qproj_mfma<<<PB_MAX, 256, 0, stream>>>(xb, wmapT, perm, rbe2, rbs2, rbc2, qp, qpb);
    rel_kernel<<<(32 * T_) / 2, 256, 0, stream>>>(qp, rpe, rel);
    attn_kernel<<<512, 256, 0, stream>>>(qpb, kpb, vpT, rel, gates, azd);
    reduce_mfma<<<dim3(PB_MAX, 4), 256, 0, stream>>>(azd, wredT3, perm, rbe2, rbs2, rbc2, z4);
    combine_out<<<(N_ * D_) / 1024, 256, 0, stream>>>(z4, out);
}